// Round 1
// baseline (759.630 us; speedup 1.0000x reference)
//
#include <hip/hip_runtime.h>
#include <hip/hip_bf16.h>

// Fused AllReduce(tp=8 sum) + residual add + RMSNorm, fp32.
// input:    [TP=8, TOKENS=4096, HIDDEN=4096] f32
// residual: [TOKENS, HIDDEN] f32
// weight:   [HIDDEN] f32
// out:      [norm (TOKENS*HIDDEN), hidden_states (TOKENS*HIDDEN)] f32 concat
//
// Memory-bound: ~738 MB compulsory traffic -> ~117 us at 6.3 TB/s.

constexpr int TP      = 8;
constexpr int TOKENS  = 4096;
constexpr int HIDDEN  = 4096;
constexpr int BLOCK   = 256;
constexpr int V4      = HIDDEN / 4;        // 1024 float4 per row
constexpr int V4_PT   = V4 / BLOCK;        // 4 float4 per thread
constexpr float EPS   = 1e-6f;

__global__ __launch_bounds__(BLOCK, 2)
void fused_ar_rmsnorm(const float* __restrict__ input,
                      const float* __restrict__ residual,
                      const float* __restrict__ weight,
                      float* __restrict__ norm_out,
                      float* __restrict__ hs_out)
{
    const int row = blockIdx.x;
    const size_t row_off = (size_t)row * HIDDEN;
    const int t = threadIdx.x;

    const float4* __restrict__ res4 = (const float4*)(residual + row_off);
    float4*       __restrict__ hs4  = (float4*)(hs_out  + row_off);
    float4*       __restrict__ no4  = (float4*)(norm_out + row_off);
    const float4* __restrict__ w4   = (const float4*)weight;

    float4 hs[V4_PT];
    float  ssq = 0.f;

    // Sum TP slices + residual; keep hidden_states in registers.
    #pragma unroll
    for (int i = 0; i < V4_PT; ++i) {
        const int idx = t + i * BLOCK;          // float4 index within row
        float4 acc = res4[idx];
        #pragma unroll
        for (int p = 0; p < TP; ++p) {
            const float4* __restrict__ in4 =
                (const float4*)(input + (size_t)p * ((size_t)TOKENS * HIDDEN) + row_off);
            const float4 v = in4[idx];
            acc.x += v.x; acc.y += v.y; acc.z += v.z; acc.w += v.w;
        }
        hs[i] = acc;
        ssq += acc.x * acc.x + acc.y * acc.y + acc.z * acc.z + acc.w * acc.w;
        hs4[idx] = acc;                          // second output: hidden_states
    }

    // Block reduction of sum of squares: wave64 shuffle, then 4-entry LDS.
    #pragma unroll
    for (int off = 32; off > 0; off >>= 1)
        ssq += __shfl_down(ssq, off, 64);

    __shared__ float red[BLOCK / 64];
    const int wave = t >> 6;
    const int lane = t & 63;
    if (lane == 0) red[wave] = ssq;
    __syncthreads();
    const float total = red[0] + red[1] + red[2] + red[3];
    const float inv = rsqrtf(total * (1.0f / HIDDEN) + EPS);

    // First output: norm = hs * inv * weight
    #pragma unroll
    for (int i = 0; i < V4_PT; ++i) {
        const int idx = t + i * BLOCK;
        const float4 wv = w4[idx];
        const float4 h  = hs[i];
        float4 o;
        o.x = h.x * inv * wv.x;
        o.y = h.y * inv * wv.y;
        o.z = h.z * inv * wv.z;
        o.w = h.w * inv * wv.w;
        no4[idx] = o;
    }
}

extern "C" void kernel_launch(void* const* d_in, const int* in_sizes, int n_in,
                              void* d_out, int out_size, void* d_ws, size_t ws_size,
                              hipStream_t stream) {
    const float* input    = (const float*)d_in[0];
    const float* residual = (const float*)d_in[1];
    const float* weight   = (const float*)d_in[2];
    float* norm_out = (float*)d_out;                       // [TOKENS*HIDDEN]
    float* hs_out   = norm_out + (size_t)TOKENS * HIDDEN;  // [TOKENS*HIDDEN]

    fused_ar_rmsnorm<<<TOKENS, BLOCK, 0, stream>>>(input, residual, weight,
                                                   norm_out, hs_out);
}